// Round 1
// baseline (764.475 us; speedup 1.0000x reference)
//
#include <hip/hip_runtime.h>

#define D_MODEL 1024
#define HEAD 64
#define TSEQ 2048
#define NB 4
#define BT (NB * TSEQ)

// ---------------------------------------------------------------------------
// Kernel 1: fused QKV projection.
// One thread per output element (row r in [0,8192), col c in [0,192)).
// c/64 selects tensor (0=q,1=k,2=v), c%64 is head dim.
// Consecutive threads share the same x row (broadcast via cache) and read
// consecutive W columns (coalesced).
// qkv layout in ws: [3][BT][HEAD], order q,k,v.
// ---------------------------------------------------------------------------
__global__ __launch_bounds__(256) void qkv_kernel(
    const float* __restrict__ x,
    const float* __restrict__ Wq, const float* __restrict__ Wk, const float* __restrict__ Wv,
    const float* __restrict__ bq, const float* __restrict__ bk, const float* __restrict__ bv,
    float* __restrict__ qkv)
{
    int gid = blockIdx.x * 256 + threadIdx.x;
    int r = gid / 192;
    int c = gid - r * 192;
    if (r >= BT) return;
    int tsel = c >> 6;   // 0=q, 1=k, 2=v
    int h = c & 63;
    const float* W;
    const float* bias;
    if (tsel == 0)      { W = Wq; bias = bq; }
    else if (tsel == 1) { W = Wk; bias = bk; }
    else                { W = Wv; bias = bv; }

    const float* xr = x + (size_t)r * D_MODEL;
    float acc = 0.f;
#pragma unroll 8
    for (int i = 0; i < D_MODEL; ++i)
        acc = fmaf(xr[i], W[(size_t)i * HEAD + h], acc);

    qkv[((size_t)tsel * BT + r) * HEAD + h] = acc + bias[h];
}

// ---------------------------------------------------------------------------
// Kernel 2: causal attention, one block (256 thr = 4 waves) per query row.
//  pass 1: scores s<=t into LDS, track max
//  pass 2: exp + sum
//  pass 3: PV accumulation; wave w handles s = w, w+4, ...; lane = head dim
// ---------------------------------------------------------------------------
__global__ __launch_bounds__(256) void attn_kernel(
    const float* __restrict__ qkv, float* __restrict__ out)
{
    __shared__ float q_s[HEAD];
    __shared__ float sc[TSEQ];   // 8 KB
    __shared__ float red[4];
    __shared__ float m_s, l_s;
    __shared__ float op[4][HEAD];

    int row = blockIdx.x;        // b*TSEQ + t
    int b = row >> 11;
    int t = row & (TSEQ - 1);
    int tid = threadIdx.x;
    int wid = tid >> 6;
    int lane = tid & 63;

    const float* qp = qkv + (size_t)row * HEAD;
    const float* kb = qkv + (size_t)BT * HEAD + (size_t)b * TSEQ * HEAD;
    const float* vb = qkv + 2 * (size_t)BT * HEAD + (size_t)b * TSEQ * HEAD;

    if (tid < HEAD) q_s[tid] = qp[tid];
    __syncthreads();

    int n = t + 1;   // number of valid (causal) keys

    // ---- pass 1: scores + local max ----
    float lmax = -3.0e38f;
    for (int s = tid; s < n; s += 256) {
        const float4* kp = (const float4*)(kb + (size_t)s * HEAD);
        float acc = 0.f;
#pragma unroll
        for (int i = 0; i < 16; ++i) {
            float4 k4 = kp[i];
            acc = fmaf(k4.x, q_s[4 * i + 0], acc);
            acc = fmaf(k4.y, q_s[4 * i + 1], acc);
            acc = fmaf(k4.z, q_s[4 * i + 2], acc);
            acc = fmaf(k4.w, q_s[4 * i + 3], acc);
        }
        acc *= 0.03125f;   // 1/sqrt(1024)
        sc[s] = acc;
        lmax = fmaxf(lmax, acc);
    }
#pragma unroll
    for (int off = 32; off > 0; off >>= 1)
        lmax = fmaxf(lmax, __shfl_down(lmax, off, 64));
    if (lane == 0) red[wid] = lmax;
    __syncthreads();
    if (tid == 0) m_s = fmaxf(fmaxf(red[0], red[1]), fmaxf(red[2], red[3]));
    __syncthreads();
    float m = m_s;

    // ---- pass 2: exp + sum ----
    float lsum = 0.f;
    for (int s = tid; s < n; s += 256) {
        float p = __expf(sc[s] - m);
        sc[s] = p;
        lsum += p;
    }
#pragma unroll
    for (int off = 32; off > 0; off >>= 1)
        lsum += __shfl_down(lsum, off, 64);
    if (lane == 0) red[wid] = lsum;
    __syncthreads();
    if (tid == 0) l_s = red[0] + red[1] + red[2] + red[3];
    __syncthreads();
    float inv_l = 1.0f / l_s;

    // ---- pass 3: PV ----
    int h = lane;
    float acc = 0.f;
    for (int s = wid; s < n; s += 4)
        acc = fmaf(sc[s], vb[(size_t)s * HEAD + h], acc);
    op[wid][h] = acc;
    __syncthreads();
    if (wid == 0)
        out[(size_t)row * HEAD + h] = (op[0][h] + op[1][h] + op[2][h] + op[3][h]) * inv_l;
}

extern "C" void kernel_launch(void* const* d_in, const int* in_sizes, int n_in,
                              void* d_out, int out_size, void* d_ws, size_t ws_size,
                              hipStream_t stream) {
    const float* x  = (const float*)d_in[0];
    const float* Wk = (const float*)d_in[1];
    const float* Wq = (const float*)d_in[2];
    const float* Wv = (const float*)d_in[3];
    const float* bk = (const float*)d_in[4];
    const float* bq = (const float*)d_in[5];
    const float* bv = (const float*)d_in[6];
    float* out = (float*)d_out;
    float* qkv = (float*)d_ws;   // [3][BT][HEAD] f32 = 6 MB

    int total = BT * 192;
    qkv_kernel<<<(total + 255) / 256, 256, 0, stream>>>(x, Wq, Wk, Wv, bq, bk, bv, qkv);
    attn_kernel<<<BT, 256, 0, stream>>>(qkv, out);
}

// Round 3
// 191.081 us; speedup vs baseline: 4.0008x; 4.0008x over previous
//
#include <hip/hip_runtime.h>
#include <hip/hip_bf16.h>

#define D_MODEL 1024
#define HEAD 64
#define TSEQ 2048
#define NB 4
#define BT (NB * TSEQ)

typedef __bf16 bf16x8 __attribute__((ext_vector_type(8)));
typedef __bf16 bf16x4 __attribute__((ext_vector_type(4)));
typedef float f32x4 __attribute__((ext_vector_type(4)));

// ---------------------------------------------------------------------------
// Kernel 1: fused QKV projection, f32 accumulate -> bf16 outputs.
//   thread = 4 consecutive rows x 4 consecutive cols of one of {q,k,v}
//   outputs: qs [BT][64] bf16 (pre-scaled by 1/sqrt(1024))
//            ks [BT][64] bf16
//            vT [NB][64][TSEQ] bf16  (transposed for MFMA B-operand loads)
// ---------------------------------------------------------------------------
__global__ __launch_bounds__(256) void qkv_kernel(
    const float* __restrict__ x,
    const float* __restrict__ Wq, const float* __restrict__ Wk, const float* __restrict__ Wv,
    const float* __restrict__ bq, const float* __restrict__ bk, const float* __restrict__ bv,
    __bf16* __restrict__ qs, __bf16* __restrict__ ks, __bf16* __restrict__ vT)
{
    int gid = blockIdx.x * 256 + threadIdx.x;
    int rg = gid / 48;          // row group: 4 rows
    int cg = gid - rg * 48;     // 0..47
    int r0 = rg * 4;
    int tsel = cg >> 4;         // 0=q 1=k 2=v
    int h = (cg & 15) * 4;

    const float* W;
    const float* bias;
    if (tsel == 0)      { W = Wq; bias = bq; }
    else if (tsel == 1) { W = Wk; bias = bk; }
    else                { W = Wv; bias = bv; }

    float acc[4][4];
#pragma unroll
    for (int rr = 0; rr < 4; ++rr)
#pragma unroll
        for (int j = 0; j < 4; ++j) acc[rr][j] = 0.f;

    const float* x0 = x + (size_t)r0 * D_MODEL;

#pragma unroll 2
    for (int i = 0; i < D_MODEL; i += 4) {
        float4 wtmp[4];
#pragma unroll
        for (int kk = 0; kk < 4; ++kk)
            wtmp[kk] = *(const float4*)(W + (size_t)(i + kk) * HEAD + h);
        const float* wv = (const float*)wtmp;
#pragma unroll
        for (int rr = 0; rr < 4; ++rr) {
            float4 xt = *(const float4*)(x0 + (size_t)rr * D_MODEL + i);
            const float* xv = (const float*)&xt;
#pragma unroll
            for (int kk = 0; kk < 4; ++kk)
#pragma unroll
                for (int j = 0; j < 4; ++j)
                    acc[rr][j] = fmaf(xv[kk], wv[kk * 4 + j], acc[rr][j]);
        }
    }

    float4 b4 = *(const float4*)(bias + h);
    const float* bb = (const float*)&b4;

    if (tsel == 0) {
        // q: scale by 1/sqrt(1024) here so scores need no extra mul
#pragma unroll
        for (int rr = 0; rr < 4; ++rr) {
            bf16x4 o;
#pragma unroll
            for (int j = 0; j < 4; ++j)
                o[j] = (__bf16)((acc[rr][j] + bb[j]) * 0.03125f);
            *(bf16x4*)(qs + (size_t)(r0 + rr) * HEAD + h) = o;
        }
    } else if (tsel == 1) {
#pragma unroll
        for (int rr = 0; rr < 4; ++rr) {
            bf16x4 o;
#pragma unroll
            for (int j = 0; j < 4; ++j)
                o[j] = (__bf16)(acc[rr][j] + bb[j]);
            *(bf16x4*)(ks + (size_t)(r0 + rr) * HEAD + h) = o;
        }
    } else {
        int b = r0 >> 11;          // batch
        int t0 = r0 & (TSEQ - 1);  // time within batch (4 consecutive)
#pragma unroll
        for (int j = 0; j < 4; ++j) {
            bf16x4 o;
#pragma unroll
            for (int rr = 0; rr < 4; ++rr)
                o[rr] = (__bf16)(acc[rr][j] + bb[j]);
            *(bf16x4*)(vT + (size_t)(b * HEAD + h + j) * TSEQ + t0) = o;
        }
    }
}

// ---------------------------------------------------------------------------
// Kernel 2: flash attention with mfma_f32_16x16x32_bf16.
// One wave (64 thr) per block; each block owns a 16-row q-tile of one batch.
// K-tiles of 32 keys; K/V fragments loaded straight from global (L2-resident).
// Online softmax per row; P transposed C->A layout via small padded LDS.
//
// MFMA layouts (gfx950, 16x16x32):
//   A frag: lane l holds A[l&15][(l>>4)*8 + i], i=0..7  (contig. 16B per lane)
//   B frag: lane l holds B[(l>>4)*8 + i][l&15]
//   C/D   : lane l holds D[(l>>4)*4 + reg][l&15]        (verified m89)
//
// Causal mask: tile needs masking iff it intersects the diagonal, i.e.
// last key in tile (kbase+31) > first row (qb). (Round-2 bug: compared
// against nk=qb+16, which skipped masking for odd q-tiles.)
// ---------------------------------------------------------------------------
__global__ __launch_bounds__(64) void attn_mfma(
    const __bf16* __restrict__ qs, const __bf16* __restrict__ ks,
    const __bf16* __restrict__ vT, float* __restrict__ out)
{
    __shared__ __align__(16) __bf16 plds[2][16 * 40];  // 40-elem row pad: banks spread

    int blk = blockIdx.x;
    int b = blk >> 7;                   // batch
    int qt = 127 - (blk & 127);         // reverse: heavy (late) q-tiles start first
    int qb = qt * 16;

    int lane = threadIdx.x;
    int g = lane >> 4;
    int c16 = lane & 15;

    const __bf16* qsb = qs + (size_t)(b * TSEQ + qb) * HEAD;
    const __bf16* kb_ = ks + (size_t)b * TSEQ * HEAD;
    const __bf16* vb_ = vT + (size_t)b * HEAD * TSEQ;

    // Q fragments (rows qb..qb+15, h split 0-31 / 32-63)
    bf16x8 qf0 = *(const bf16x8*)(qsb + c16 * HEAD + g * 8);
    bf16x8 qf1 = *(const bf16x8*)(qsb + c16 * HEAD + 32 + g * 8);

    f32x4 o0 = {0.f, 0.f, 0.f, 0.f}, o1 = o0, o2 = o0, o3 = o0;
    float m[4], l[4];
#pragma unroll
    for (int j = 0; j < 4; ++j) { m[j] = -3.0e38f; l[j] = 0.f; }

    int nk = qb + 16;                   // causal: keys needed
    int ntiles = (nk + 31) >> 5;

    for (int ti = 0; ti < ntiles; ++ti) {
        int kbase = ti * 32;

        // ---- QK^T: S[16 rows][32 keys] as two 16x16 C-frags ----
        const __bf16* kr0 = kb_ + (size_t)(kbase + c16) * HEAD + g * 8;
        bf16x8 k00 = *(const bf16x8*)(kr0);
        bf16x8 k01 = *(const bf16x8*)(kr0 + 32);
        const __bf16* kr1 = kr0 + 16 * HEAD;
        bf16x8 k10 = *(const bf16x8*)(kr1);
        bf16x8 k11 = *(const bf16x8*)(kr1 + 32);

        f32x4 z = {0.f, 0.f, 0.f, 0.f};
        f32x4 s0 = __builtin_amdgcn_mfma_f32_16x16x32_bf16(qf0, k00, z, 0, 0, 0);
        s0 = __builtin_amdgcn_mfma_f32_16x16x32_bf16(qf1, k01, s0, 0, 0, 0);
        f32x4 s1 = __builtin_amdgcn_mfma_f32_16x16x32_bf16(qf0, k10, z, 0, 0, 0);
        s1 = __builtin_amdgcn_mfma_f32_16x16x32_bf16(qf1, k11, s1, 0, 0, 0);

        // ---- causal mask on any tile that touches the diagonal ----
        if (kbase + 31 > qb) {
#pragma unroll
            for (int j = 0; j < 4; ++j) {
                int qr = qb + 4 * g + j;
                if (kbase + c16 > qr)      s0[j] = -3.0e38f;
                if (kbase + 16 + c16 > qr) s1[j] = -3.0e38f;
            }
        }

        // ---- online softmax ----
        float al[4], p0[4], p1[4], rs[4];
#pragma unroll
        for (int j = 0; j < 4; ++j) {
            float v = fmaxf(s0[j], s1[j]);
            v = fmaxf(v, __shfl_xor(v, 1, 16));
            v = fmaxf(v, __shfl_xor(v, 2, 16));
            v = fmaxf(v, __shfl_xor(v, 4, 16));
            v = fmaxf(v, __shfl_xor(v, 8, 16));
            float mn = fmaxf(m[j], v);
            al[j] = __expf(m[j] - mn);
            m[j] = mn;
        }
#pragma unroll
        for (int j = 0; j < 4; ++j) {
            p0[j] = __expf(s0[j] - m[j]);
            p1[j] = __expf(s1[j] - m[j]);
            float r = p0[j] + p1[j];
            r += __shfl_xor(r, 1, 16);
            r += __shfl_xor(r, 2, 16);
            r += __shfl_xor(r, 4, 16);
            r += __shfl_xor(r, 8, 16);
            rs[j] = r;
        }
#pragma unroll
        for (int j = 0; j < 4; ++j) {
            l[j] = l[j] * al[j] + rs[j];
            o0[j] *= al[j]; o1[j] *= al[j]; o2[j] *= al[j]; o3[j] *= al[j];
        }

        // ---- P: C-layout -> A-layout through LDS (bf16) ----
        __bf16* pl = plds[ti & 1];
#pragma unroll
        for (int j = 0; j < 4; ++j) {
            pl[(4 * g + j) * 40 + c16]      = (__bf16)p0[j];
            pl[(4 * g + j) * 40 + c16 + 16] = (__bf16)p1[j];
        }
        __syncthreads();
        bf16x8 pf = *(const bf16x8*)(pl + c16 * 40 + g * 8);

        // ---- PV: O[16][64] += P[16][32] x V[32][64] ----
        const __bf16* vbase = vb_ + kbase + g * 8;
        o0 = __builtin_amdgcn_mfma_f32_16x16x32_bf16(pf, *(const bf16x8*)(vbase + (size_t)(c16) * TSEQ), o0, 0, 0, 0);
        o1 = __builtin_amdgcn_mfma_f32_16x16x32_bf16(pf, *(const bf16x8*)(vbase + (size_t)(c16 + 16) * TSEQ), o1, 0, 0, 0);
        o2 = __builtin_amdgcn_mfma_f32_16x16x32_bf16(pf, *(const bf16x8*)(vbase + (size_t)(c16 + 32) * TSEQ), o2, 0, 0, 0);
        o3 = __builtin_amdgcn_mfma_f32_16x16x32_bf16(pf, *(const bf16x8*)(vbase + (size_t)(c16 + 48) * TSEQ), o3, 0, 0, 0);
    }

    // ---- epilogue: normalize + store f32 ----
    float inv[4];
#pragma unroll
    for (int j = 0; j < 4; ++j) inv[j] = 1.0f / l[j];

    float* orow = out + (size_t)(b * TSEQ + qb) * HEAD;
#pragma unroll
    for (int j = 0; j < 4; ++j) {
        int r = 4 * g + j;
        orow[(size_t)r * HEAD + c16]      = o0[j] * inv[j];
        orow[(size_t)r * HEAD + c16 + 16] = o1[j] * inv[j];
        orow[(size_t)r * HEAD + c16 + 32] = o2[j] * inv[j];
        orow[(size_t)r * HEAD + c16 + 48] = o3[j] * inv[j];
    }
}

extern "C" void kernel_launch(void* const* d_in, const int* in_sizes, int n_in,
                              void* d_out, int out_size, void* d_ws, size_t ws_size,
                              hipStream_t stream) {
    const float* x  = (const float*)d_in[0];
    const float* Wk = (const float*)d_in[1];
    const float* Wq = (const float*)d_in[2];
    const float* Wv = (const float*)d_in[3];
    const float* bk = (const float*)d_in[4];
    const float* bq = (const float*)d_in[5];
    const float* bv = (const float*)d_in[6];
    float* out = (float*)d_out;

    __bf16* qs = (__bf16*)d_ws;                        // [BT][64]   1 MB
    __bf16* ks = qs + (size_t)BT * HEAD;               // [BT][64]   1 MB
    __bf16* vT = ks + (size_t)BT * HEAD;               // [NB][64][TSEQ] 1 MB

    // 8192/4 row-groups * 48 col-groups = 98304 threads = 384 blocks
    qkv_kernel<<<384, 256, 0, stream>>>(x, Wq, Wk, Wv, bq, bk, bv, qs, ks, vT);
    // 4 batches * 128 q-tiles = 512 one-wave blocks
    attn_mfma<<<512, 64, 0, stream>>>(qs, ks, vT, out);
}

// Round 4
// 108.261 us; speedup vs baseline: 7.0614x; 1.7650x over previous
//
#include <hip/hip_runtime.h>
#include <hip/hip_bf16.h>

#define D_MODEL 1024
#define HEAD 64
#define TSEQ 2048
#define NB 4
#define BT (NB * TSEQ)

typedef __bf16 bf16x8 __attribute__((ext_vector_type(8)));
typedef __bf16 bf16x4 __attribute__((ext_vector_type(4)));
typedef float f32x4 __attribute__((ext_vector_type(4)));

// ---------------------------------------------------------------------------
// Kernel 0: W transpose + bf16 convert.
// wt[3][64][1024]: wt[(tsel*64 + col)*1024 + k] = W_tsel[k][col], bf16.
// Makes GEMM B-fragments contiguous bf16x8 loads.
// One block per 64x64 tile (48 blocks).
// ---------------------------------------------------------------------------
__global__ __launch_bounds__(256) void wt_kernel(
    const float* __restrict__ Wq, const float* __restrict__ Wk,
    const float* __restrict__ Wv, __bf16* __restrict__ wt)
{
    __shared__ float tile[64][65];
    int tsel = blockIdx.x >> 4;
    int k0 = (blockIdx.x & 15) * 64;
    const float* W = tsel == 0 ? Wq : (tsel == 1 ? Wk : Wv);
    int tid = threadIdx.x;
#pragma unroll
    for (int i = 0; i < 16; ++i) {
        int idx = i * 256 + tid;
        int k = idx >> 6, c = idx & 63;
        tile[k][c] = W[(size_t)(k0 + k) * 64 + c];
    }
    __syncthreads();
#pragma unroll
    for (int i = 0; i < 16; ++i) {
        int idx = i * 256 + tid;
        int c = idx >> 6, k = idx & 63;
        wt[(size_t)(tsel * 64 + c) * 1024 + k0 + k] = (__bf16)tile[k][c];
    }
}

// ---------------------------------------------------------------------------
// Kernel 1: QKV projection as MFMA GEMM.  M=8192, K=1024, N=192.
// Block = one 16-row strip, 4 waves; wave w covers K range [w*256, w*256+256),
// full 16x192 output. Cross-wave f32 reduce through LDS, then fused
// bias/scale/bf16 epilogue (q pre-scaled by 1/sqrt(1024), V transposed).
//
// MFMA 16x16x32 layouts (verified by round-3 attn kernel):
//   A: lane l holds A[l&15][(l>>4)*8+i]   B: lane l holds B[(l>>4)*8+i][l&15]
//   D: lane l holds D[(l>>4)*4+r][l&15]
// ---------------------------------------------------------------------------
__global__ __launch_bounds__(256) void qkv_gemm(
    const float* __restrict__ x, const __bf16* __restrict__ wt,
    const float* __restrict__ bq, const float* __restrict__ bk, const float* __restrict__ bv,
    __bf16* __restrict__ qs, __bf16* __restrict__ ks, __bf16* __restrict__ vT)
{
    __shared__ f32x4 red[4][12][64];   // 48 KB

    int r0 = blockIdx.x * 16;
    int tid = threadIdx.x;
    int w = tid >> 6;
    int lane = tid & 63;
    int c16 = lane & 15, g = lane >> 4;

    f32x4 acc[12];
#pragma unroll
    for (int j = 0; j < 12; ++j) acc[j] = (f32x4){0.f, 0.f, 0.f, 0.f};

    const float* xbase = x + (size_t)(r0 + c16) * D_MODEL + g * 8;
    const __bf16* wbase = wt + (size_t)c16 * D_MODEL + g * 8;

#pragma unroll
    for (int kt = 0; kt < 8; ++kt) {
        int k0 = w * 256 + kt * 32;
        float4 xa = *(const float4*)(xbase + k0);
        float4 xb = *(const float4*)(xbase + k0 + 4);
        bf16x8 af;
        af[0] = (__bf16)xa.x; af[1] = (__bf16)xa.y;
        af[2] = (__bf16)xa.z; af[3] = (__bf16)xa.w;
        af[4] = (__bf16)xb.x; af[5] = (__bf16)xb.y;
        af[6] = (__bf16)xb.z; af[7] = (__bf16)xb.w;

        const __bf16* wk = wbase + k0;
#pragma unroll
        for (int j = 0; j < 12; ++j) {
            bf16x8 bfr = *(const bf16x8*)(wk + (size_t)j * 16 * D_MODEL);
            acc[j] = __builtin_amdgcn_mfma_f32_16x16x32_bf16(af, bfr, acc[j], 0, 0, 0);
        }
    }

#pragma unroll
    for (int j = 0; j < 12; ++j) red[w][j][lane] = acc[j];
    __syncthreads();

    // wave w finalizes tiles j = w, w+4, w+8 (one of each q/k/v)
#pragma unroll
    for (int jj = 0; jj < 3; ++jj) {
        int j = w + jj * 4;
        f32x4 s = red[0][j][lane] + red[1][j][lane] + red[2][j][lane] + red[3][j][lane];
        int tsel = j >> 2;
        int cm = (j & 3) * 16 + c16;     // column within its matrix (0..63)
        const float* bias = tsel == 0 ? bq : (tsel == 1 ? bk : bv);
        float bval = bias[cm];
        if (tsel == 0) {
#pragma unroll
            for (int r = 0; r < 4; ++r)
                qs[(size_t)(r0 + g * 4 + r) * HEAD + cm] = (__bf16)((s[r] + bval) * 0.03125f);
        } else if (tsel == 1) {
#pragma unroll
            for (int r = 0; r < 4; ++r)
                ks[(size_t)(r0 + g * 4 + r) * HEAD + cm] = (__bf16)(s[r] + bval);
        } else {
#pragma unroll
            for (int r = 0; r < 4; ++r) {
                int row = r0 + g * 4 + r;
                int b = row >> 11, t = row & (TSEQ - 1);
                vT[(size_t)(b * HEAD + cm) * TSEQ + t] = (__bf16)(s[r] + bval);
            }
        }
    }
}

// ---------------------------------------------------------------------------
// Kernel 2: flash attention with mfma_f32_16x16x32_bf16 (unchanged, passing).
// ---------------------------------------------------------------------------
__global__ __launch_bounds__(64) void attn_mfma(
    const __bf16* __restrict__ qs, const __bf16* __restrict__ ks,
    const __bf16* __restrict__ vT, float* __restrict__ out)
{
    __shared__ __align__(16) __bf16 plds[2][16 * 40];

    int blk = blockIdx.x;
    int b = blk >> 7;
    int qt = 127 - (blk & 127);         // heavy q-tiles first
    int qb = qt * 16;

    int lane = threadIdx.x;
    int g = lane >> 4;
    int c16 = lane & 15;

    const __bf16* qsb = qs + (size_t)(b * TSEQ + qb) * HEAD;
    const __bf16* kb_ = ks + (size_t)b * TSEQ * HEAD;
    const __bf16* vb_ = vT + (size_t)b * HEAD * TSEQ;

    bf16x8 qf0 = *(const bf16x8*)(qsb + c16 * HEAD + g * 8);
    bf16x8 qf1 = *(const bf16x8*)(qsb + c16 * HEAD + 32 + g * 8);

    f32x4 o0 = {0.f, 0.f, 0.f, 0.f}, o1 = o0, o2 = o0, o3 = o0;
    float m[4], l[4];
#pragma unroll
    for (int j = 0; j < 4; ++j) { m[j] = -3.0e38f; l[j] = 0.f; }

    int nk = qb + 16;
    int ntiles = (nk + 31) >> 5;

    for (int ti = 0; ti < ntiles; ++ti) {
        int kbase = ti * 32;

        const __bf16* kr0 = kb_ + (size_t)(kbase + c16) * HEAD + g * 8;
        bf16x8 k00 = *(const bf16x8*)(kr0);
        bf16x8 k01 = *(const bf16x8*)(kr0 + 32);
        const __bf16* kr1 = kr0 + 16 * HEAD;
        bf16x8 k10 = *(const bf16x8*)(kr1);
        bf16x8 k11 = *(const bf16x8*)(kr1 + 32);

        f32x4 z = {0.f, 0.f, 0.f, 0.f};
        f32x4 s0 = __builtin_amdgcn_mfma_f32_16x16x32_bf16(qf0, k00, z, 0, 0, 0);
        s0 = __builtin_amdgcn_mfma_f32_16x16x32_bf16(qf1, k01, s0, 0, 0, 0);
        f32x4 s1 = __builtin_amdgcn_mfma_f32_16x16x32_bf16(qf0, k10, z, 0, 0, 0);
        s1 = __builtin_amdgcn_mfma_f32_16x16x32_bf16(qf1, k11, s1, 0, 0, 0);

        if (kbase + 31 > qb) {
#pragma unroll
            for (int j = 0; j < 4; ++j) {
                int qr = qb + 4 * g + j;
                if (kbase + c16 > qr)      s0[j] = -3.0e38f;
                if (kbase + 16 + c16 > qr) s1[j] = -3.0e38f;
            }
        }

        float al[4], p0[4], p1[4], rs[4];
#pragma unroll
        for (int j = 0; j < 4; ++j) {
            float v = fmaxf(s0[j], s1[j]);
            v = fmaxf(v, __shfl_xor(v, 1, 16));
            v = fmaxf(v, __shfl_xor(v, 2, 16));
            v = fmaxf(v, __shfl_xor(v, 4, 16));
            v = fmaxf(v, __shfl_xor(v, 8, 16));
            float mn = fmaxf(m[j], v);
            al[j] = __expf(m[j] - mn);
            m[j] = mn;
        }
#pragma unroll
        for (int j = 0; j < 4; ++j) {
            p0[j] = __expf(s0[j] - m[j]);
            p1[j] = __expf(s1[j] - m[j]);
            float r = p0[j] + p1[j];
            r += __shfl_xor(r, 1, 16);
            r += __shfl_xor(r, 2, 16);
            r += __shfl_xor(r, 4, 16);
            r += __shfl_xor(r, 8, 16);
            rs[j] = r;
        }
#pragma unroll
        for (int j = 0; j < 4; ++j) {
            l[j] = l[j] * al[j] + rs[j];
            o0[j] *= al[j]; o1[j] *= al[j]; o2[j] *= al[j]; o3[j] *= al[j];
        }

        __bf16* pl = plds[ti & 1];
#pragma unroll
        for (int j = 0; j < 4; ++j) {
            pl[(4 * g + j) * 40 + c16]      = (__bf16)p0[j];
            pl[(4 * g + j) * 40 + c16 + 16] = (__bf16)p1[j];
        }
        __syncthreads();
        bf16x8 pf = *(const bf16x8*)(pl + c16 * 40 + g * 8);

        const __bf16* vbase = vb_ + kbase + g * 8;
        o0 = __builtin_amdgcn_mfma_f32_16x16x32_bf16(pf, *(const bf16x8*)(vbase + (size_t)(c16) * TSEQ), o0, 0, 0, 0);
        o1 = __builtin_amdgcn_mfma_f32_16x16x32_bf16(pf, *(const bf16x8*)(vbase + (size_t)(c16 + 16) * TSEQ), o1, 0, 0, 0);
        o2 = __builtin_amdgcn_mfma_f32_16x16x32_bf16(pf, *(const bf16x8*)(vbase + (size_t)(c16 + 32) * TSEQ), o2, 0, 0, 0);
        o3 = __builtin_amdgcn_mfma_f32_16x16x32_bf16(pf, *(const bf16x8*)(vbase + (size_t)(c16 + 48) * TSEQ), o3, 0, 0, 0);
    }

    float inv[4];
#pragma unroll
    for (int j = 0; j < 4; ++j) inv[j] = 1.0f / l[j];

    float* orow = out + (size_t)(b * TSEQ + qb) * HEAD;
#pragma unroll
    for (int j = 0; j < 4; ++j) {
        int r = 4 * g + j;
        orow[(size_t)r * HEAD + c16]      = o0[j] * inv[j];
        orow[(size_t)r * HEAD + c16 + 16] = o1[j] * inv[j];
        orow[(size_t)r * HEAD + c16 + 32] = o2[j] * inv[j];
        orow[(size_t)r * HEAD + c16 + 48] = o3[j] * inv[j];
    }
}

extern "C" void kernel_launch(void* const* d_in, const int* in_sizes, int n_in,
                              void* d_out, int out_size, void* d_ws, size_t ws_size,
                              hipStream_t stream) {
    const float* x  = (const float*)d_in[0];
    const float* Wk = (const float*)d_in[1];
    const float* Wq = (const float*)d_in[2];
    const float* Wv = (const float*)d_in[3];
    const float* bk = (const float*)d_in[4];
    const float* bq = (const float*)d_in[5];
    const float* bv = (const float*)d_in[6];
    float* out = (float*)d_out;

    __bf16* qs = (__bf16*)d_ws;                        // [BT][64]        1 MB
    __bf16* ks = qs + (size_t)BT * HEAD;               // [BT][64]        1 MB
    __bf16* vT = ks + (size_t)BT * HEAD;               // [NB][64][TSEQ]  1 MB
    __bf16* wt = vT + (size_t)BT * HEAD;               // [192][1024]     384 KB

    wt_kernel<<<48, 256, 0, stream>>>(Wq, Wk, Wv, wt);
    qkv_gemm<<<BT / 16, 256, 0, stream>>>(x, wt, bq, bk, bv, qs, ks, vT);
    attn_mfma<<<512, 64, 0, stream>>>(qs, ks, vT, out);
}

// Round 5
// 68.663 us; speedup vs baseline: 11.1337x; 1.5767x over previous
//
#include <hip/hip_runtime.h>
#include <hip/hip_bf16.h>

#define D_MODEL 1024
#define HEAD 64
#define TSEQ 2048
#define NB 4
#define BT (NB * TSEQ)

typedef __bf16 bf16x8 __attribute__((ext_vector_type(8)));
typedef __bf16 bf16x4 __attribute__((ext_vector_type(4)));
typedef float f32x4 __attribute__((ext_vector_type(4)));

// ---------------------------------------------------------------------------
// Kernel 0: W transpose + bf16 convert. wt[(tsel*64+col)*1024 + k] = W[k][col]
// ---------------------------------------------------------------------------
__global__ __launch_bounds__(256) void wt_kernel(
    const float* __restrict__ Wq, const float* __restrict__ Wk,
    const float* __restrict__ Wv, __bf16* __restrict__ wt)
{
    __shared__ float tile[64][65];
    int tsel = blockIdx.x >> 4;
    int k0 = (blockIdx.x & 15) * 64;
    const float* W = tsel == 0 ? Wq : (tsel == 1 ? Wk : Wv);
    int tid = threadIdx.x;
#pragma unroll
    for (int i = 0; i < 16; ++i) {
        int idx = i * 256 + tid;
        int k = idx >> 6, c = idx & 63;
        tile[k][c] = W[(size_t)(k0 + k) * 64 + c];
    }
    __syncthreads();
#pragma unroll
    for (int i = 0; i < 16; ++i) {
        int idx = i * 256 + tid;
        int c = idx >> 6, k = idx & 63;
        wt[(size_t)(tsel * 64 + c) * 1024 + k0 + k] = (__bf16)tile[k][c];
    }
}

// ---------------------------------------------------------------------------
// Kernel 1: QKV projection as MFMA GEMM (unchanged from round 4).
// ---------------------------------------------------------------------------
__global__ __launch_bounds__(256) void qkv_gemm(
    const float* __restrict__ x, const __bf16* __restrict__ wt,
    const float* __restrict__ bq, const float* __restrict__ bk, const float* __restrict__ bv,
    __bf16* __restrict__ qs, __bf16* __restrict__ ks, __bf16* __restrict__ vT)
{
    __shared__ f32x4 red[4][12][64];   // 48 KB

    int r0 = blockIdx.x * 16;
    int tid = threadIdx.x;
    int w = tid >> 6;
    int lane = tid & 63;
    int c16 = lane & 15, g = lane >> 4;

    f32x4 acc[12];
#pragma unroll
    for (int j = 0; j < 12; ++j) acc[j] = (f32x4){0.f, 0.f, 0.f, 0.f};

    const float* xbase = x + (size_t)(r0 + c16) * D_MODEL + g * 8;
    const __bf16* wbase = wt + (size_t)c16 * D_MODEL + g * 8;

#pragma unroll
    for (int kt = 0; kt < 8; ++kt) {
        int k0 = w * 256 + kt * 32;
        float4 xa = *(const float4*)(xbase + k0);
        float4 xb = *(const float4*)(xbase + k0 + 4);
        bf16x8 af;
        af[0] = (__bf16)xa.x; af[1] = (__bf16)xa.y;
        af[2] = (__bf16)xa.z; af[3] = (__bf16)xa.w;
        af[4] = (__bf16)xb.x; af[5] = (__bf16)xb.y;
        af[6] = (__bf16)xb.z; af[7] = (__bf16)xb.w;

        const __bf16* wk = wbase + k0;
#pragma unroll
        for (int j = 0; j < 12; ++j) {
            bf16x8 bfr = *(const bf16x8*)(wk + (size_t)j * 16 * D_MODEL);
            acc[j] = __builtin_amdgcn_mfma_f32_16x16x32_bf16(af, bfr, acc[j], 0, 0, 0);
        }
    }

#pragma unroll
    for (int j = 0; j < 12; ++j) red[w][j][lane] = acc[j];
    __syncthreads();

#pragma unroll
    for (int jj = 0; jj < 3; ++jj) {
        int j = w + jj * 4;
        f32x4 s = red[0][j][lane] + red[1][j][lane] + red[2][j][lane] + red[3][j][lane];
        int tsel = j >> 2;
        int cm = (j & 3) * 16 + c16;
        const float* bias = tsel == 0 ? bq : (tsel == 1 ? bk : bv);
        float bval = bias[cm];
        if (tsel == 0) {
#pragma unroll
            for (int r = 0; r < 4; ++r)
                qs[(size_t)(r0 + g * 4 + r) * HEAD + cm] = (__bf16)((s[r] + bval) * 0.03125f);
        } else if (tsel == 1) {
#pragma unroll
            for (int r = 0; r < 4; ++r)
                ks[(size_t)(r0 + g * 4 + r) * HEAD + cm] = (__bf16)(s[r] + bval);
        } else {
#pragma unroll
            for (int r = 0; r < 4; ++r) {
                int row = r0 + g * 4 + r;
                int b = row >> 11, t = row & (TSEQ - 1);
                vT[(size_t)(b * HEAD + cm) * TSEQ + t] = (__bf16)(s[r] + bval);
            }
        }
    }
}

// ---------------------------------------------------------------------------
// Kernel 2: flash attention, 4-way key-split per q-tile.
// Block = 4 waves, one 16-row q-tile. Wave w handles k-tiles w, w+4, ...
// with private online (m,l,O) state and a private LDS P-buffer (no barrier
// in the loop: waves have different trip counts; within-wave LDS RAW is
// handled by compiler lgkmcnt). One barrier + LDS combine at the end.
//
// MFMA 16x16x32 layouts: A: lane=(g,c16) holds A[c16][g*8+i];
// B: B[g*8+i][c16]; D: D[g*4+r][c16].
// ---------------------------------------------------------------------------
__global__ __launch_bounds__(256) void attn_mfma(
    const __bf16* __restrict__ qs, const __bf16* __restrict__ ks,
    const __bf16* __restrict__ vT, float* __restrict__ out)
{
    __shared__ __align__(16) __bf16 plds[4][16 * 40];   // 5 KB, per-wave
    __shared__ __align__(16) f32x4 ocomb[4][4][64];     // 16 KB [wave][cg][lane]
    __shared__ float mcomb[4][16];                      // [wave][row]
    __shared__ float lcomb[4][16];

    int blk = blockIdx.x;
    int b = blk >> 7;
    int qt = 127 - (blk & 127);         // heavy q-tiles first
    int qb = qt * 16;

    int tid = threadIdx.x;
    int w = tid >> 6;
    int lane = tid & 63;
    int g = lane >> 4;
    int c16 = lane & 15;

    const __bf16* qsb = qs + (size_t)(b * TSEQ + qb) * HEAD;
    const __bf16* kb_ = ks + (size_t)b * TSEQ * HEAD;
    const __bf16* vb_ = vT + (size_t)b * HEAD * TSEQ;

    bf16x8 qf0 = *(const bf16x8*)(qsb + c16 * HEAD + g * 8);
    bf16x8 qf1 = *(const bf16x8*)(qsb + c16 * HEAD + 32 + g * 8);

    f32x4 o0 = {0.f, 0.f, 0.f, 0.f}, o1 = o0, o2 = o0, o3 = o0;
    float m[4], l[4];
#pragma unroll
    for (int j = 0; j < 4; ++j) { m[j] = -3.0e38f; l[j] = 0.f; }

    int nt = (qb + 47) >> 5;            // number of 32-key tiles
    __bf16* pl = plds[w];

    for (int ti = w; ti < nt; ti += 4) {
        int kbase = ti * 32;

        // ---- QK^T ----
        const __bf16* kr0 = kb_ + (size_t)(kbase + c16) * HEAD + g * 8;
        bf16x8 k00 = *(const bf16x8*)(kr0);
        bf16x8 k01 = *(const bf16x8*)(kr0 + 32);
        const __bf16* kr1 = kr0 + 16 * HEAD;
        bf16x8 k10 = *(const bf16x8*)(kr1);
        bf16x8 k11 = *(const bf16x8*)(kr1 + 32);

        f32x4 z = {0.f, 0.f, 0.f, 0.f};
        f32x4 s0 = __builtin_amdgcn_mfma_f32_16x16x32_bf16(qf0, k00, z, 0, 0, 0);
        s0 = __builtin_amdgcn_mfma_f32_16x16x32_bf16(qf1, k01, s0, 0, 0, 0);
        f32x4 s1 = __builtin_amdgcn_mfma_f32_16x16x32_bf16(qf0, k10, z, 0, 0, 0);
        s1 = __builtin_amdgcn_mfma_f32_16x16x32_bf16(qf1, k11, s1, 0, 0, 0);

        // ---- causal mask (only the diagonal tile triggers) ----
        if (kbase + 31 > qb) {
#pragma unroll
            for (int j = 0; j < 4; ++j) {
                int qr = qb + 4 * g + j;
                if (kbase + c16 > qr)      s0[j] = -3.0e38f;
                if (kbase + 16 + c16 > qr) s1[j] = -3.0e38f;
            }
        }

        // ---- online softmax (per-wave state) ----
        float al[4], p0[4], p1[4], rs[4];
#pragma unroll
        for (int j = 0; j < 4; ++j) {
            float v = fmaxf(s0[j], s1[j]);
            v = fmaxf(v, __shfl_xor(v, 1, 16));
            v = fmaxf(v, __shfl_xor(v, 2, 16));
            v = fmaxf(v, __shfl_xor(v, 4, 16));
            v = fmaxf(v, __shfl_xor(v, 8, 16));
            float mn = fmaxf(m[j], v);
            al[j] = __expf(m[j] - mn);
            m[j] = mn;
        }
#pragma unroll
        for (int j = 0; j < 4; ++j) {
            p0[j] = __expf(s0[j] - m[j]);
            p1[j] = __expf(s1[j] - m[j]);
            float r = p0[j] + p1[j];
            r += __shfl_xor(r, 1, 16);
            r += __shfl_xor(r, 2, 16);
            r += __shfl_xor(r, 4, 16);
            r += __shfl_xor(r, 8, 16);
            rs[j] = r;
        }
#pragma unroll
        for (int j = 0; j < 4; ++j) {
            l[j] = l[j] * al[j] + rs[j];
            o0[j] *= al[j]; o1[j] *= al[j]; o2[j] *= al[j]; o3[j] *= al[j];
        }

        // ---- P: C-layout -> A-layout via private LDS (no barrier) ----
#pragma unroll
        for (int j = 0; j < 4; ++j) {
            pl[(4 * g + j) * 40 + c16]      = (__bf16)p0[j];
            pl[(4 * g + j) * 40 + c16 + 16] = (__bf16)p1[j];
        }
        bf16x8 pf = *(const bf16x8*)(pl + c16 * 40 + g * 8);

        // ---- PV ----
        const __bf16* vbase = vb_ + kbase + g * 8;
        o0 = __builtin_amdgcn_mfma_f32_16x16x32_bf16(pf, *(const bf16x8*)(vbase + (size_t)(c16) * TSEQ), o0, 0, 0, 0);
        o1 = __builtin_amdgcn_mfma_f32_16x16x32_bf16(pf, *(const bf16x8*)(vbase + (size_t)(c16 + 16) * TSEQ), o1, 0, 0, 0);
        o2 = __builtin_amdgcn_mfma_f32_16x16x32_bf16(pf, *(const bf16x8*)(vbase + (size_t)(c16 + 32) * TSEQ), o2, 0, 0, 0);
        o3 = __builtin_amdgcn_mfma_f32_16x16x32_bf16(pf, *(const bf16x8*)(vbase + (size_t)(c16 + 48) * TSEQ), o3, 0, 0, 0);
    }

    // ---- publish partials ----
    ocomb[w][0][lane] = o0;
    ocomb[w][1][lane] = o1;
    ocomb[w][2][lane] = o2;
    ocomb[w][3][lane] = o3;
    if (c16 == 0) {
#pragma unroll
        for (int j = 0; j < 4; ++j) {
            mcomb[w][4 * g + j] = m[j];
            lcomb[w][4 * g + j] = l[j];
        }
    }
    __syncthreads();

    // ---- combine: wave w finalizes column-group w ----
    float M[4];
#pragma unroll
    for (int j = 0; j < 4; ++j) {
        int row = 4 * g + j;
        M[j] = fmaxf(fmaxf(mcomb[0][row], mcomb[1][row]),
                     fmaxf(mcomb[2][row], mcomb[3][row]));
    }
    f32x4 O = {0.f, 0.f, 0.f, 0.f};
    float L[4] = {0.f, 0.f, 0.f, 0.f};
#pragma unroll
    for (int sw = 0; sw < 4; ++sw) {
        f32x4 po = ocomb[sw][w][lane];
#pragma unroll
        for (int j = 0; j < 4; ++j) {
            int row = 4 * g + j;
            float e = __expf(mcomb[sw][row] - M[j]);
            L[j] += lcomb[sw][row] * e;
            O[j] += po[j] * e;
        }
    }
    float* obase = out + (size_t)(b * TSEQ + qb) * HEAD + w * 16 + c16;
#pragma unroll
    for (int j = 0; j < 4; ++j)
        obase[(size_t)(4 * g + j) * HEAD] = O[j] / L[j];
}

extern "C" void kernel_launch(void* const* d_in, const int* in_sizes, int n_in,
                              void* d_out, int out_size, void* d_ws, size_t ws_size,
                              hipStream_t stream) {
    const float* x  = (const float*)d_in[0];
    const float* Wk = (const float*)d_in[1];
    const float* Wq = (const float*)d_in[2];
    const float* Wv = (const float*)d_in[3];
    const float* bk = (const float*)d_in[4];
    const float* bq = (const float*)d_in[5];
    const float* bv = (const float*)d_in[6];
    float* out = (float*)d_out;

    __bf16* qs = (__bf16*)d_ws;                        // [BT][64]        1 MB
    __bf16* ks = qs + (size_t)BT * HEAD;               // [BT][64]        1 MB
    __bf16* vT = ks + (size_t)BT * HEAD;               // [NB][64][TSEQ]  1 MB
    __bf16* wt = vT + (size_t)BT * HEAD;               // [192][1024]     384 KB

    wt_kernel<<<48, 256, 0, stream>>>(Wq, Wk, Wv, wt);
    qkv_gemm<<<BT / 16, 256, 0, stream>>>(x, wt, bq, bk, bv, qs, ks, vT);
    attn_mfma<<<512, 256, 0, stream>>>(qs, ks, vT, out);
}